// Round 1
// baseline (837.767 us; speedup 1.0000x reference)
//
#include <hip/hip_runtime.h>
#include <hip/hip_bf16.h>

// NCMOpenMax: probas = softmax(cos(X[n], muK[k]) over k), N=262144, K=512, d=128.
// Strategy: normalize muK -> bf16 (kernel 1, ws), then fused bf16-MFMA GEMM with
// norm folded into logit scale + in-register softmax (kernel 2). Write-bound:
// 512 MiB output is the floor (~102 us at 6.3 TB/s).

using floatx4 = __attribute__((ext_vector_type(4))) float;
using shortx8 = __attribute__((ext_vector_type(8))) short;   // 8 x bf16 (4 VGPRs)

__device__ __forceinline__ short f2bf(float f) {
  // round-to-nearest-even fp32 -> bf16 (NaN not a concern for this data)
  unsigned u = __builtin_bit_cast(unsigned, f);
  u += 0x7fffu + ((u >> 16) & 1u);
  return (short)(u >> 16);
}

// ---- Kernel 1: mn[c][k] = muK[c][k] / max(||muK[c]||, eps), bf16, one wave/row.
__global__ void norm_mu_kernel(const float* __restrict__ muK, short* __restrict__ mn) {
  int gid  = blockIdx.x * blockDim.x + threadIdx.x;
  int row  = gid >> 6;
  int lane = gid & 63;
  if (row >= 512) return;
  float2 v = ((const float2*)(muK + row * 128))[lane];   // 2 elems/lane
  float ss = v.x * v.x + v.y * v.y;
#pragma unroll
  for (int m = 32; m >= 1; m >>= 1) ss += __shfl_xor(ss, m, 64);
  float inv = rsqrtf(fmaxf(ss, 1e-16f));                 // eps=1e-8 on the norm
  short2 o;
  o.x = f2bf(v.x * inv);
  o.y = f2bf(v.y * inv);
  ((short2*)(mn + row * 128))[lane] = o;
}

// ---- Kernel 2: block = 4 waves = 256 thr. Block owns 64 rows; wave w owns cols
// [128w, 128w+128). 4x8 tiles of mfma_f32_16x16x32_bf16 per wave.
__global__ __launch_bounds__(256, 2)
void cos_softmax_kernel(const float* __restrict__ X,
                        const short* __restrict__ mn,
                        float* __restrict__ out) {
  const int lane = threadIdx.x & 63;
  const int wave = threadIdx.x >> 6;     // 0..3
  const int c15  = lane & 15;
  const int quad = lane >> 4;            // 0..3
  const int rb   = blockIdx.x * 64;      // row base
  const int cb   = wave * 128;           // col base for this wave

  floatx4 acc[4][8];
#pragma unroll
  for (int rt = 0; rt < 4; ++rt)
#pragma unroll
    for (int ct = 0; ct < 8; ++ct)
      acc[rt][ct] = (floatx4){0.f, 0.f, 0.f, 0.f};

  float sumsq[4] = {0.f, 0.f, 0.f, 0.f};

  // K-loop over d=128 in 4 steps of 32.
#pragma unroll
  for (int kk = 0; kk < 4; ++kk) {
    // A fragments: lane holds X[rb + rt*16 + c15][kk*32 + quad*8 + j], j=0..7
    shortx8 afr[4];
#pragma unroll
    for (int rt = 0; rt < 4; ++rt) {
      const float* p = X + (size_t)(rb + rt * 16 + c15) * 128 + kk * 32 + quad * 8;
      float4 u0 = *(const float4*)p;
      float4 u1 = *(const float4*)(p + 4);
      sumsq[rt] += u0.x * u0.x + u0.y * u0.y + u0.z * u0.z + u0.w * u0.w
                 + u1.x * u1.x + u1.y * u1.y + u1.z * u1.z + u1.w * u1.w;
      afr[rt] = (shortx8){ f2bf(u0.x), f2bf(u0.y), f2bf(u0.z), f2bf(u0.w),
                           f2bf(u1.x), f2bf(u1.y), f2bf(u1.z), f2bf(u1.w) };
    }
    // B fragments: lane holds mn[cb + ct*16 + c15][kk*32 + quad*8 + j]
    shortx8 bfr[8];
#pragma unroll
    for (int ct = 0; ct < 8; ++ct) {
      const short* p = mn + (size_t)(cb + ct * 16 + c15) * 128 + kk * 32 + quad * 8;
      bfr[ct] = *(const shortx8*)p;
    }
#pragma unroll
    for (int rt = 0; rt < 4; ++rt)
#pragma unroll
      for (int ct = 0; ct < 8; ++ct)
        acc[rt][ct] = __builtin_amdgcn_mfma_f32_16x16x32_bf16(afr[rt], bfr[ct], acc[rt][ct], 0, 0, 0);
  }

  // Full ||X[row]||^2 for row rt*16 + c15 into every lane (reduce across quads).
#pragma unroll
  for (int rt = 0; rt < 4; ++rt) {
    sumsq[rt] += __shfl_xor(sumsq[rt], 16, 64);
    sumsq[rt] += __shfl_xor(sumsq[rt], 32, 64);
  }

  // exp(acc * invnorm) in place + per-(rt,reg) partial sums over this wave's cols.
  float psum[4][4];
#pragma unroll
  for (int rt = 0; rt < 4; ++rt) {
    float inv[4];
#pragma unroll
    for (int reg = 0; reg < 4; ++reg) {
      // acc row index is quad*4+reg; fetch its norm^2 from a lane with c15 == that row
      float n2 = __shfl(sumsq[rt], (lane & 48) | (quad * 4 + reg), 64);
      inv[reg] = rsqrtf(fmaxf(n2, 1e-16f));
      psum[rt][reg] = 0.f;
    }
#pragma unroll
    for (int ct = 0; ct < 8; ++ct)
#pragma unroll
      for (int reg = 0; reg < 4; ++reg) {
        float e = __expf(acc[rt][ct][reg] * inv[reg]);
        acc[rt][ct][reg] = e;
        psum[rt][reg] += e;
      }
    // reduce over the 16 lanes (c15) of the quad group -> sum over 128 cols
#pragma unroll
    for (int reg = 0; reg < 4; ++reg) {
#pragma unroll
      for (int m = 1; m <= 8; m <<= 1)
        psum[rt][reg] += __shfl_xor(psum[rt][reg], m, 64);
    }
  }

  // Cross-wave (cross-column-strip) sum via LDS.
  __shared__ float wsum[4][64];
  __shared__ float tot[64];
  if (c15 == 0) {
#pragma unroll
    for (int rt = 0; rt < 4; ++rt)
#pragma unroll
      for (int reg = 0; reg < 4; ++reg)
        wsum[wave][rt * 16 + quad * 4 + reg] = psum[rt][reg];
  }
  __syncthreads();
  if (threadIdx.x < 64)
    tot[threadIdx.x] = wsum[0][threadIdx.x] + wsum[1][threadIdx.x]
                     + wsum[2][threadIdx.x] + wsum[3][threadIdx.x];
  __syncthreads();

  // Scale and store (nontemporal: 512 MiB streaming output, keep out of L2).
#pragma unroll
  for (int rt = 0; rt < 4; ++rt) {
    float rtot[4];
#pragma unroll
    for (int reg = 0; reg < 4; ++reg)
      rtot[reg] = 1.0f / tot[rt * 16 + quad * 4 + reg];
#pragma unroll
    for (int ct = 0; ct < 8; ++ct) {
      float* po = out + (size_t)(rb + rt * 16 + quad * 4) * 512 + cb + ct * 16 + c15;
#pragma unroll
      for (int reg = 0; reg < 4; ++reg)
        __builtin_nontemporal_store(acc[rt][ct][reg] * rtot[reg], po + (size_t)reg * 512);
    }
  }
}

extern "C" void kernel_launch(void* const* d_in, const int* in_sizes, int n_in,
                              void* d_out, int out_size, void* d_ws, size_t ws_size,
                              hipStream_t stream) {
  const float* X   = (const float*)d_in[0];   // [262144, 128]
  const float* muK = (const float*)d_in[1];   // [512, 128]
  float* out = (float*)d_out;                 // [262144, 512]
  short* mn  = (short*)d_ws;                  // 512*128 bf16 = 128 KiB scratch

  norm_mu_kernel<<<128, 256, 0, stream>>>(muK, mn);
  cos_softmax_kernel<<<4096, 256, 0, stream>>>(X, mn, out);
}